// Round 12
// baseline (911.599 us; speedup 1.0000x reference)
//
#include <hip/hip_runtime.h>
#include <math.h>

#define S_LEN 2048
#define DMODEL 256
#define NHEAD 4
#define HDIM 64
#define NLAYER 4
#define FFDIM 2048
#define INDIM 512
#define BATCH 4
#define NTOK (BATCH * S_LEN) /* 8192 */
#define EPSV 1e-5f
#define KSPLIT 4

typedef __attribute__((ext_vector_type(8))) short frag8;
typedef __attribute__((ext_vector_type(4))) float f32x4v;
typedef unsigned short u16;
typedef unsigned int u32;

__device__ __forceinline__ float pe_val(int s, int d) {
    const float c = 0.035977892f; // ln(10000)/256
    float dv = expf(-(float)(d & ~1) * c);
    float arg = (float)s * dv;
    return (d & 1) ? cosf(arg) : sinf(arg);
}

__device__ __forceinline__ u16 f2bf(float f) {
    union { float f; unsigned u; } v; v.f = f;
    unsigned r = v.u + 0x7fffu + ((v.u >> 16) & 1u);
    return (u16)(r >> 16);
}
__device__ __forceinline__ float bf2f(u16 h) {
    union { u32 u; float f; } v; v.u = (u32)h << 16; return v.f;
}
// pack two fp32 into (bf16(hi)<<16)|bf16(lo), truncation, one v_perm_b32
__device__ __forceinline__ u32 pk2bf(float lo, float hi) {
    union { float f; u32 u; } a, b; a.f = lo; b.f = hi;
    return __builtin_amdgcn_perm(b.u, a.u, 0x07060302u);
}
__device__ __forceinline__ void load_lds16(const u16* g, u16* l) {
    __builtin_amdgcn_global_load_lds(
        (const __attribute__((address_space(1))) unsigned int*)g,
        (__attribute__((address_space(3))) unsigned int*)l, 16, 0, 0);
}

// ---------------------------------------------------------------------------
// Convert x + all layer weights fp32 -> bf16; also zero the LN tail counters.
// ---------------------------------------------------------------------------
__global__ __launch_bounds__(256) void cvt_all(
    const float* __restrict__ x, const float* __restrict__ W_in,
    const float* __restrict__ qkv_w, const float* __restrict__ out_w,
    const float* __restrict__ ff1_w, const float* __restrict__ ff2_w,
    u16* __restrict__ xb, u16* __restrict__ W_in_b,
    u16* __restrict__ qkv_w_b, u16* __restrict__ out_w_b,
    u16* __restrict__ ff1_w_b, u16* __restrict__ ff2_w_b,
    int* __restrict__ cnt)
{
    const int i = blockIdx.x * 256 + threadIdx.x;   // 0..2392063
    if (blockIdx.x == 0 && threadIdx.x < 128) cnt[threadIdx.x] = 0;
    const float* src; u16* dst; int base;
    if (i < 1048576)      { src = x;     dst = xb;      base = 0; }
    else if (i < 1081344) { src = W_in;  dst = W_in_b;  base = 1048576; }
    else if (i < 1277952) { src = qkv_w; dst = qkv_w_b; base = 1081344; }
    else if (i < 1343488) { src = out_w; dst = out_w_b; base = 1277952; }
    else if (i < 1867776) { src = ff1_w; dst = ff1_w_b; base = 1343488; }
    else                  { src = ff2_w; dst = ff2_w_b; base = 1867776; }
    const int e = (i - base) * 4;
    const float4 v = *(const float4*)(src + e);
    ushort4 o;
    o.x = f2bf(v.x); o.y = f2bf(v.y); o.z = f2bf(v.z); o.w = f2bf(v.w);
    *(ushort4*)(dst + e) = o;
}

// ---------------------------------------------------------------------------
// bf16 MFMA GEMM, 128x128 tile, BK=32, double-buffered single-barrier K-loop.
// MODE 2: relu bf16 (ff1).
// ---------------------------------------------------------------------------
template <int MODE>
__global__ __launch_bounds__(256) void gemm_mfma(
    const u16* __restrict__ A, const u16* __restrict__ W,
    const float* __restrict__ bias, u16* __restrict__ Cb,
    int M, int N, int K)
{
    __shared__ __align__(16) u16 As[2][128 * 32];
    __shared__ __align__(16) u16 Bs[2][128 * 32];
    const int t = threadIdx.x;
    const int w = t >> 6, lane = t & 63;
    const int col = lane & 15, quad = lane >> 4;
    const int qx = (quad ^ ((col >> 1) & 3)) * 8;
    const int m0 = blockIdx.x * 128, n0 = blockIdx.y * 128;
    const int wm = (w >> 1) * 64, wn = (w & 1) * 64;

    const int r0 = lane >> 2;
    const int kc = ((lane & 3) ^ ((lane >> 3) & 3)) * 8;
    const u16* pA0 = A + (size_t)(m0 + (w * 2 + 0) * 16 + r0) * K + kc;
    const u16* pA1 = A + (size_t)(m0 + (w * 2 + 1) * 16 + r0) * K + kc;
    const u16* pB0 = W + (size_t)(n0 + (w * 2 + 0) * 16 + r0) * K + kc;
    const u16* pB1 = W + (size_t)(n0 + (w * 2 + 1) * 16 + r0) * K + kc;
    const int oA0 = (w * 2 + 0) * 512, oA1 = (w * 2 + 1) * 512;

    f32x4v acc[4][4];
#pragma unroll
    for (int i = 0; i < 4; ++i)
#pragma unroll
        for (int j = 0; j < 4; ++j) acc[i][j] = (f32x4v){0.f, 0.f, 0.f, 0.f};

    load_lds16(pA0, &As[0][oA0]);
    load_lds16(pA1, &As[0][oA1]);
    load_lds16(pB0, &Bs[0][oA0]);
    load_lds16(pB1, &Bs[0][oA1]);

    const int NIT = K >> 5;
    for (int it = 0; it < NIT; ++it) {
        const int cur = it & 1;
        __syncthreads();
        if (it + 1 < NIT) {
            const int kb = (it + 1) << 5;
            load_lds16(pA0 + kb, &As[cur ^ 1][oA0]);
            load_lds16(pA1 + kb, &As[cur ^ 1][oA1]);
            load_lds16(pB0 + kb, &Bs[cur ^ 1][oA0]);
            load_lds16(pB1 + kb, &Bs[cur ^ 1][oA1]);
        }

        frag8 a[4], b[4];
#pragma unroll
        for (int i = 0; i < 4; ++i)
            a[i] = *(const frag8*)&As[cur][(wm + i * 16 + col) * 32 + qx];
#pragma unroll
        for (int j = 0; j < 4; ++j)
            b[j] = *(const frag8*)&Bs[cur][(wn + j * 16 + col) * 32 + qx];
#pragma unroll
        for (int i = 0; i < 4; ++i)
#pragma unroll
            for (int j = 0; j < 4; ++j)
                acc[i][j] = __builtin_amdgcn_mfma_f32_16x16x32_bf16(
                    a[i], b[j], acc[i][j], 0, 0, 0);
    }

#pragma unroll
    for (int j = 0; j < 4; ++j) {
        const int cn = n0 + wn + j * 16 + col;
        const float bv = bias[cn];
#pragma unroll
        for (int i = 0; i < 4; ++i) {
            const int cmb = m0 + wm + i * 16 + quad * 4;
#pragma unroll
            for (int r = 0; r < 4; ++r) {
                float v = acc[i][j][r] + bv;
                if (MODE == 2) v = fmaxf(v, 0.f);
                Cb[(size_t)(cmb + r) * N + cn] = f2bf(v);
            }
        }
    }
}

// ---------------------------------------------------------------------------
// bf16 MFMA GEMM, 64x64 tile, BK=64, double-buffered single-barrier K-loop.
// MODE 1: +posenc | MODE 4: bf16 + V^T side-write (aux=vt, cols>=512)
// MODE 5: fused residual (Cb = gemm + bias + aux)
// MODE 6: A = K-split attention partials combined during A-staging + residual
// MODE 5/6 additionally perform the LayerNorm TAIL: each block writes per-row
// partial stats for its 64-col slice; the last of the 4 col-blocks per m-tile
// (device-scope counter) LNs the 64 rows of sab -> hb. N must be 256.
// ---------------------------------------------------------------------------
template <int MODE>
__global__ __launch_bounds__(256) void gemm64k(
    const u16* __restrict__ A, const u16* __restrict__ W,
    const float* __restrict__ bias, u16* __restrict__ Cb,
    u16* __restrict__ aux, const float* __restrict__ lp,
    const float* __restrict__ lnw, const float* __restrict__ lnb,
    float* __restrict__ pstats, int* __restrict__ cnt,
    int M, int N, int K)
{
    __shared__ __align__(16) u16 As[2][64 * 64];
    __shared__ __align__(16) u16 Bs[2][64 * 64];
    __shared__ int lastflag;
    const int t = threadIdx.x;
    const int w = t >> 6, lane = t & 63;
    const int col = lane & 15, quad = lane >> 4;
    const int px0 = ((quad ^ (col & 7))) * 8;
    const int px1 = px0 ^ 32;
    const int m0 = blockIdx.x * 64, n0 = blockIdx.y * 64;
    const int wm = (w >> 1) * 32, wn = (w & 1) * 32;

    const int sr = lane >> 3;
    const int lc = ((lane & 7) ^ sr) * 8;
    const u16* pA0 = A + (size_t)(m0 + w * 16 + sr) * K + lc;
    const u16* pA1 = A + (size_t)(m0 + w * 16 + 8 + sr) * K + lc;
    const u16* pB0 = W + (size_t)(n0 + w * 16 + sr) * K + lc;
    const u16* pB1 = W + (size_t)(n0 + w * 16 + 8 + sr) * K + lc;
    const int o0 = (w * 16) * 64, o1 = (w * 16 + 8) * 64;

    f32x4v acc[2][2];
#pragma unroll
    for (int i = 0; i < 2; ++i)
#pragma unroll
        for (int j = 0; j < 2; ++j) acc[i][j] = (f32x4v){0.f, 0.f, 0.f, 0.f};

    auto stageA = [&](int it, int buf) {
        if (MODE == 6) {
            const int hh = it;  // K=256: head index == K-iter
#pragma unroll
            for (int pos = 0; pos < 2; ++pos) {
                const int m = m0 + w * 16 + pos * 8 + sr;
                const int q = m & (S_LEN - 1);
                const int bh = (m >> 11) * 4 + hh;
                const size_t basei = (((size_t)bh) * S_LEN + q) * 64 + lc;
                float l = 0.f;
                float o[8] = {0.f, 0.f, 0.f, 0.f, 0.f, 0.f, 0.f, 0.f};
#pragma unroll
                for (int ksx = 0; ksx < KSPLIT; ++ksx) {
                    const uint4 pv = *(const uint4*)(A + (size_t)ksx * 16 * S_LEN * 64 + basei);
                    o[0] += bf2f((u16)(pv.x & 0xffff)); o[1] += bf2f((u16)(pv.x >> 16));
                    o[2] += bf2f((u16)(pv.y & 0xffff)); o[3] += bf2f((u16)(pv.y >> 16));
                    o[4] += bf2f((u16)(pv.z & 0xffff)); o[5] += bf2f((u16)(pv.z >> 16));
                    o[6] += bf2f((u16)(pv.w & 0xffff)); o[7] += bf2f((u16)(pv.w >> 16));
                    l += lp[((size_t)ksx * 16 + bh) * S_LEN + q];
                }
                const float inv = 1.f / l;
                uint4 pk;
                pk.x = ((u32)f2bf(o[1] * inv) << 16) | f2bf(o[0] * inv);
                pk.y = ((u32)f2bf(o[3] * inv) << 16) | f2bf(o[2] * inv);
                pk.z = ((u32)f2bf(o[5] * inv) << 16) | f2bf(o[4] * inv);
                pk.w = ((u32)f2bf(o[7] * inv) << 16) | f2bf(o[6] * inv);
                *(uint4*)&As[buf][(pos ? o1 : o0) + lane * 8] = pk;
            }
        } else {
            const int kb = it << 6;
            load_lds16(pA0 + kb, &As[buf][o0]);
            load_lds16(pA1 + kb, &As[buf][o1]);
        }
    };
    auto stageB = [&](int it, int buf) {
        const int kb = it << 6;
        load_lds16(pB0 + kb, &Bs[buf][o0]);
        load_lds16(pB1 + kb, &Bs[buf][o1]);
    };

    stageA(0, 0);
    stageB(0, 0);

    const int NIT = K >> 6;
    for (int it = 0; it < NIT; ++it) {
        const int cur = it & 1;
        __syncthreads();
        if (it + 1 < NIT) {
            stageA(it + 1, cur ^ 1);
            stageB(it + 1, cur ^ 1);
        }
#pragma unroll
        for (int kh = 0; kh < 2; ++kh) {
            const int px = kh ? px1 : px0;
            frag8 a[2], b[2];
#pragma unroll
            for (int i = 0; i < 2; ++i)
                a[i] = *(const frag8*)&As[cur][(wm + i * 16 + col) * 64 + px];
#pragma unroll
            for (int j = 0; j < 2; ++j)
                b[j] = *(const frag8*)&Bs[cur][(wn + j * 16 + col) * 64 + px];
#pragma unroll
            for (int i = 0; i < 2; ++i)
#pragma unroll
                for (int j = 0; j < 2; ++j)
                    acc[i][j] = __builtin_amdgcn_mfma_f32_16x16x32_bf16(
                        a[i], b[j], acc[i][j], 0, 0, 0);
        }
    }

    float ps[2][4], ps2[2][4];
    if (MODE == 5 || MODE == 6) {
#pragma unroll
        for (int i = 0; i < 2; ++i)
#pragma unroll
            for (int r = 0; r < 4; ++r) { ps[i][r] = 0.f; ps2[i][r] = 0.f; }
    }

#pragma unroll
    for (int j = 0; j < 2; ++j) {
        const int cn = n0 + wn + j * 16 + col;
        const float bv = bias[cn];
#pragma unroll
        for (int i = 0; i < 2; ++i) {
            const int cmb = m0 + wm + i * 16 + quad * 4;
            float vv[4];
#pragma unroll
            for (int r = 0; r < 4; ++r) {
                float v = acc[i][j][r] + bv;
                if (MODE == 1) v += pe_val((cmb + r) & (S_LEN - 1), cn);
                if (MODE == 5 || MODE == 6) {
                    v += bf2f(aux[(size_t)(cmb + r) * N + cn]);
                    ps[i][r] += v;
                    ps2[i][r] += v * v;
                }
                vv[r] = v;
                Cb[(size_t)(cmb + r) * N + cn] = f2bf(v);
            }
            if (MODE == 4 && cn >= 512) {   // V^T side-write: vt[bh][d][s]
                const int dg = cn - 512;
                const int bh = (cmb >> 11) * 4 + (dg >> 6);
                uint2 pk;
                pk.x = ((u32)f2bf(vv[1]) << 16) | f2bf(vv[0]);
                pk.y = ((u32)f2bf(vv[3]) << 16) | f2bf(vv[2]);
                *(uint2*)&aux[((size_t)bh * 64 + (dg & 63)) * S_LEN + (cmb & 2047)] = pk;
            }
        }
    }

    if constexpr (MODE == 5 || MODE == 6) {
        // per-row partial stats over this block's 64-col slice (per wave-half)
#pragma unroll
        for (int i = 0; i < 2; ++i)
#pragma unroll
            for (int r = 0; r < 4; ++r) {
#pragma unroll
                for (int msk = 1; msk < 16; msk <<= 1) {
                    ps[i][r] += __shfl_xor(ps[i][r], msk);
                    ps2[i][r] += __shfl_xor(ps2[i][r], msk);
                }
                if (col == 0) {
                    const int row = m0 + wm + i * 16 + quad * 4 + r;
                    const int pp = (n0 >> 6) * 2 + (w & 1);
                    *(float2*)&pstats[2 * ((size_t)pp * NTOK + row)] =
                        (float2){ps[i][r], ps2[i][r]};
                }
            }
        __threadfence();               // release this block's sab/pstats
        __syncthreads();
        if (t == 0) {
            const int old = atomicAdd(&cnt[blockIdx.x], 1);
            lastflag = ((old & 3) == 3);
        }
        __syncthreads();
        if (!lastflag) return;
        __threadfence();               // acquire sibling blocks' writes

        // LN tail: 64 rows x 256 cols; thread = (row = t>>2, 64-col segment)
        const int rl = t >> 2;
        const int cs = (t & 3) * 64;
        const int grow = m0 + rl;
        float s = 0.f, s2 = 0.f;
#pragma unroll
        for (int pp = 0; pp < 8; ++pp) {
            const float2 st = *(const float2*)&pstats[2 * ((size_t)pp * NTOK + grow)];
            s += st.x; s2 += st.y;
        }
        const float mu = s * (1.f / 256.f);
        const float var = s2 * (1.f / 256.f) - mu * mu;
        const float rs = rsqrtf(var + EPSV);
#pragma unroll
        for (int c4 = 0; c4 < 16; ++c4) {
            const int c = cs + c4 * 4;
            const ushort4 xv = *(const ushort4*)&Cb[(size_t)grow * 256 + c];
            const float4 wv4 = *(const float4*)&lnw[c];
            const float4 bv4 = *(const float4*)&lnb[c];
            ushort4 o;
            o.x = f2bf((bf2f(xv.x) - mu) * rs * wv4.x + bv4.x);
            o.y = f2bf((bf2f(xv.y) - mu) * rs * wv4.y + bv4.y);
            o.z = f2bf((bf2f(xv.z) - mu) * rs * wv4.z + bv4.z);
            o.w = f2bf((bf2f(xv.w) - mu) * rs * wv4.w + bv4.w);
            *(ushort4*)&aux[(size_t)grow * 256 + c] = o;   // aux == hb
        }
    }
}

// ---------------------------------------------------------------------------
// Flash attention, K-split partial pass (round-11 dbuf structure, 40 KB LDS).
// ---------------------------------------------------------------------------
__global__ __launch_bounds__(256) void attn_part(const u16* __restrict__ qkv,
                                                 const u16* __restrict__ vt,
                                                 u16* __restrict__ Opart,
                                                 float* __restrict__ lpart)
{
    __shared__ __align__(16) u16 Ks[2][2][64 * 32];   // [buf][k-half]
    __shared__ __align__(16) u16 Vt[2][2][64 * 32];
    __shared__ __align__(16) u16 Ps[4][2][512];       // [wave][key-half]

    const int t = threadIdx.x;
    const int w = t >> 6, lane = t & 63;
    const int col = lane & 15, quad = lane >> 4;
    const int sq = (col >> 1) & 3;
    const int qx = (quad ^ sq) * 8;
    const int bh = blockIdx.x, b = bh >> 2, hh = bh & 3;
    const int qt = blockIdx.y, ks = blockIdx.z;

    const float SCL = 0.125f * 1.44269504f;  // log2(e)/8, folded into Q

    frag8 qf[2][2];
#pragma unroll
    for (int qg = 0; qg < 2; ++qg) {
        const int qrow = qt * 128 + w * 32 + qg * 16 + col;
        const u16* qp = qkv + (size_t)(b * S_LEN + qrow) * 768 + hh * HDIM;
        const frag8 r0 = *(const frag8*)(qp + quad * 8);
        const frag8 r1 = *(const frag8*)(qp + 32 + quad * 8);
#pragma unroll
        for (int e = 0; e < 8; ++e) {
            qf[qg][0][e] = (short)f2bf(bf2f((u16)r0[e]) * SCL);
            qf[qg][1][e] = (short)f2bf(bf2f((u16)r1[e]) * SCL);
        }
    }
    frag8 ones;
#pragma unroll
    for (int e = 0; e < 8; ++e) ones[e] = (short)0x3F80;  // bf16 1.0

    f32x4v Oacc[2][4], lacc[2];
#pragma unroll
    for (int qg = 0; qg < 2; ++qg) {
#pragma unroll
        for (int dt = 0; dt < 4; ++dt) Oacc[qg][dt] = (f32x4v){0.f, 0.f, 0.f, 0.f};
        lacc[qg] = (f32x4v){0.f, 0.f, 0.f, 0.f};
    }

    const int srow = w * 16 + (lane >> 2);
    const int sseg = ((lane & 3) ^ ((lane >> 3) & 3)) * 8;
    const int kb0 = ks * (S_LEN / KSPLIT);
    const u16* kbase = qkv + (size_t)(b * S_LEN + kb0 + srow) * 768
                       + 256 + hh * HDIM + sseg;
    const u16* vbase = vt + ((size_t)bh * 64 + srow) * S_LEN + kb0 + sseg;
    const int so = w * 512;

    load_lds16(kbase, &Ks[0][0][so]);
    load_lds16(kbase + 32, &Ks[0][1][so]);
    load_lds16(vbase, &Vt[0][0][so]);
    load_lds16(vbase + 32, &Vt[0][1][so]);

    const int NT = S_LEN / KSPLIT / 64;   // 8 tiles
    for (int kt = 0; kt < NT; ++kt) {
        const int cur = kt & 1;
        __syncthreads();
        if (kt + 1 < NT) {
            const u16* kp = kbase + (size_t)(kt + 1) * 64 * 768;
            const u16* vp = vbase + (kt + 1) * 64;
            load_lds16(kp, &Ks[cur ^ 1][0][so]);
            load_lds16(kp + 32, &Ks[cur ^ 1][1][so]);
            load_lds16(vp, &Vt[cur ^ 1][0][so]);
            load_lds16(vp + 32, &Vt[cur ^ 1][1][so]);
        }

        frag8 pf[2][2];
#pragma unroll
        for (int qg = 0; qg < 2; ++qg) {
#pragma unroll
            for (int nt = 0; nt < 4; ++nt) {
                const frag8 k0 = *(const frag8*)&Ks[cur][0][(nt * 16 + col) * 32 + qx];
                const frag8 k1 = *(const frag8*)&Ks[cur][1][(nt * 16 + col) * 32 + qx];
                f32x4v s = (f32x4v){0.f, 0.f, 0.f, 0.f};
                s = __builtin_amdgcn_mfma_f32_16x16x32_bf16(k0, qf[qg][0], s, 0, 0, 0);
                s = __builtin_amdgcn_mfma_f32_16x16x32_bf16(k1, qf[qg][1], s, 0, 0, 0);
                const float p0 = __builtin_amdgcn_exp2f(s[0]);
                const float p1 = __builtin_amdgcn_exp2f(s[1]);
                const float p2 = __builtin_amdgcn_exp2f(s[2]);
                const float p3 = __builtin_amdgcn_exp2f(s[3]);
                const int c = (nt & 1) * 2 + (quad >> 1);
                const int poff = col * 32 + ((c ^ sq) * 8) + (quad & 1) * 4;
                uint2 pk;
                pk.x = pk2bf(p0, p1);
                pk.y = pk2bf(p2, p3);
                *(uint2*)&Ps[w][nt >> 1][poff] = pk;
            }
            pf[qg][0] = *(const frag8*)&Ps[w][0][col * 32 + qx];
            pf[qg][1] = *(const frag8*)&Ps[w][1][col * 32 + qx];
        }

#pragma unroll
        for (int dt = 0; dt < 4; ++dt) {
            const frag8 v0 = *(const frag8*)&Vt[cur][0][(dt * 16 + col) * 32 + qx];
            const frag8 v1 = *(const frag8*)&Vt[cur][1][(dt * 16 + col) * 32 + qx];
#pragma unroll
            for (int qg = 0; qg < 2; ++qg) {
                Oacc[qg][dt] = __builtin_amdgcn_mfma_f32_16x16x32_bf16(
                    v0, pf[qg][0], Oacc[qg][dt], 0, 0, 0);
                Oacc[qg][dt] = __builtin_amdgcn_mfma_f32_16x16x32_bf16(
                    v1, pf[qg][1], Oacc[qg][dt], 0, 0, 0);
            }
        }
#pragma unroll
        for (int qg = 0; qg < 2; ++qg) {
            lacc[qg] = __builtin_amdgcn_mfma_f32_16x16x32_bf16(
                ones, pf[qg][0], lacc[qg], 0, 0, 0);
            lacc[qg] = __builtin_amdgcn_mfma_f32_16x16x32_bf16(
                ones, pf[qg][1], lacc[qg], 0, 0, 0);
        }
    }

#pragma unroll
    for (int qg = 0; qg < 2; ++qg) {
        const int qrow = qt * 128 + w * 32 + qg * 16 + col;
        u16* op = Opart + (((size_t)ks * 16 + bh) * S_LEN + qrow) * 64;
#pragma unroll
        for (int dt = 0; dt < 4; ++dt) {
            uint2 pk;
            pk.x = pk2bf(Oacc[qg][dt][0], Oacc[qg][dt][1]);
            pk.y = pk2bf(Oacc[qg][dt][2], Oacc[qg][dt][3]);
            *(uint2*)(op + dt * 16 + quad * 4) = pk;
        }
        if (quad == 0)
            lpart[((size_t)ks * 16 + bh) * S_LEN + qrow] = lacc[qg][0];
    }
}

__global__ __launch_bounds__(256) void final_proj(const u16* __restrict__ hb,
                                                  const float* __restrict__ Wfc,
                                                  const float* __restrict__ bfc,
                                                  float* __restrict__ out)
{
    const int idx = blockIdx.x * 256 + threadIdx.x;
    const int b = idx >> 9;
    const int o = idx & 511;
    const u16* hp = hb + (size_t)(b * S_LEN + S_LEN - 1) * DMODEL;
    const float* wp = Wfc + (size_t)o * DMODEL;
    float s = 0.f;
#pragma unroll 4
    for (int d = 0; d < DMODEL; ++d) s += bf2f(hp[d]) * wp[d];
    out[idx] = s + bfc[o];
}

extern "C" void kernel_launch(void* const* d_in, const int* in_sizes, int n_in,
                              void* d_out, int out_size, void* d_ws, size_t ws_size,
                              hipStream_t stream)
{
    const float* x     = (const float*)d_in[0];
    const float* W_in  = (const float*)d_in[1];
    const float* b_in  = (const float*)d_in[2];
    const float* qkv_w = (const float*)d_in[3];
    const float* qkv_b = (const float*)d_in[4];
    const float* out_w = (const float*)d_in[5];
    const float* out_b = (const float*)d_in[6];
    const float* ln1_w = (const float*)d_in[7];
    const float* ln1_b = (const float*)d_in[8];
    const float* ff1_w = (const float*)d_in[9];
    const float* ff1_b = (const float*)d_in[10];
    const float* ff2_w = (const float*)d_in[11];
    const float* ff2_b = (const float*)d_in[12];
    const float* ln2_w = (const float*)d_in[13];
    const float* ln2_b = (const float*)d_in[14];
    const float* W_fc  = (const float*)d_in[15];
    const float* b_fc  = (const float*)d_in[16];
    float* out = (float*)d_out;

    char* p = (char*)d_ws;
    u16* hb    = (u16*)p;  p += (size_t)NTOK * DMODEL * 2;   // 4 MB
    u16* sab   = (u16*)p;  p += (size_t)NTOK * DMODEL * 2;   // 4 MB
    u16* xb    = (u16*)p;  p += (size_t)NTOK * INDIM * 2;    // 8 MB
    u16* qkvb  = (u16*)p;  p += (size_t)NTOK * 768 * 2;      // 12 MB
    u16* ffb   = (u16*)p;  p += (size_t)NTOK * FFDIM * 2;    // 32 MB
    u16* vtb   = (u16*)p;  p += (size_t)16 * 64 * S_LEN * 2; // 4 MB
    float* lpart = (float*)p; p += (size_t)KSPLIT * 16 * S_LEN * 4; // 512 KB
    float* pstats = (float*)p; p += (size_t)8 * NTOK * 2 * 4;       // 512 KB
    int* cnt = (int*)p; p += 512;
    u16* W_in_b  = (u16*)p; p += (size_t)131072 * 2;
    u16* qkv_w_b = (u16*)p; p += (size_t)786432 * 2;
    u16* out_w_b = (u16*)p; p += (size_t)262144 * 2;
    u16* ff1_w_b = (u16*)p; p += (size_t)2097152 * 2;
    u16* ff2_w_b = (u16*)p; p += (size_t)2097152 * 2;
    if (ws_size < (size_t)79691776) return;

    u16* Opart = ffb;   // aliases ffb (disjoint lifetime within layer)

    cvt_all<<<9344, 256, 0, stream>>>(x, W_in, qkv_w, out_w, ff1_w, ff2_w,
                                      xb, W_in_b, qkv_w_b, out_w_b, ff1_w_b,
                                      ff2_w_b, cnt);

    // input projection + posenc -> hb (bf16)
    gemm64k<1><<<dim3(NTOK / 64, DMODEL / 64), 256, 0, stream>>>(
        xb, W_in_b, b_in, hb, nullptr, nullptr, nullptr, nullptr,
        nullptr, nullptr, NTOK, DMODEL, INDIM);

    for (int l = 0; l < NLAYER; ++l) {
        gemm64k<4><<<dim3(NTOK / 64, 768 / 64), 256, 0, stream>>>(
            hb, qkv_w_b + (size_t)l * 768 * DMODEL, qkv_b + l * 768,
            qkvb, vtb, nullptr, nullptr, nullptr, nullptr, nullptr,
            NTOK, 768, DMODEL);
        attn_part<<<dim3(BATCH * NHEAD, S_LEN / 128, KSPLIT), 256, 0, stream>>>(
            qkvb, vtb, Opart, lpart);
        // out-proj: fused K-split combine + residual + LN1 tail -> hb
        gemm64k<6><<<dim3(NTOK / 64, DMODEL / 64), 256, 0, stream>>>(
            Opart, out_w_b + (size_t)l * DMODEL * DMODEL, out_b + l * DMODEL,
            sab, hb, lpart, ln1_w + l * DMODEL, ln1_b + l * DMODEL,
            pstats, cnt, NTOK, DMODEL, DMODEL);
        gemm_mfma<2><<<dim3(NTOK / 128, FFDIM / 128), 256, 0, stream>>>(
            hb, ff1_w_b + (size_t)l * FFDIM * DMODEL, ff1_b + l * FFDIM,
            ffb, NTOK, FFDIM, DMODEL);
        // ff2: fused residual + LN2 tail -> hb
        gemm64k<5><<<dim3(NTOK / 64, DMODEL / 64), 256, 0, stream>>>(
            ffb, ff2_w_b + (size_t)l * DMODEL * FFDIM, ff2_b + l * DMODEL,
            sab, hb, nullptr, ln2_w + l * DMODEL, ln2_b + l * DMODEL,
            pstats, cnt, NTOK, DMODEL, FFDIM);
    }

    final_proj<<<8, 256, 0, stream>>>(hb, W_fc, b_fc, out);
}

// Round 13
// 524.008 us; speedup vs baseline: 1.7397x; 1.7397x over previous
//
#include <hip/hip_runtime.h>
#include <math.h>

#define S_LEN 2048
#define DMODEL 256
#define NHEAD 4
#define HDIM 64
#define NLAYER 4
#define FFDIM 2048
#define INDIM 512
#define BATCH 4
#define NTOK (BATCH * S_LEN) /* 8192 */
#define EPSV 1e-5f
#define KSPLIT 4

typedef __attribute__((ext_vector_type(8))) short frag8;
typedef __attribute__((ext_vector_type(4))) float f32x4v;
typedef unsigned short u16;
typedef unsigned int u32;

__device__ __forceinline__ float pe_val(int s, int d) {
    const float c = 0.035977892f; // ln(10000)/256
    float dv = expf(-(float)(d & ~1) * c);
    float arg = (float)s * dv;
    return (d & 1) ? cosf(arg) : sinf(arg);
}

__device__ __forceinline__ u16 f2bf(float f) {
    union { float f; unsigned u; } v; v.f = f;
    unsigned r = v.u + 0x7fffu + ((v.u >> 16) & 1u);
    return (u16)(r >> 16);
}
__device__ __forceinline__ float bf2f(u16 h) {
    union { u32 u; float f; } v; v.u = (u32)h << 16; return v.f;
}
// pack two fp32 into (bf16(hi)<<16)|bf16(lo), truncation, one v_perm_b32
__device__ __forceinline__ u32 pk2bf(float lo, float hi) {
    union { float f; u32 u; } a, b; a.f = lo; b.f = hi;
    return __builtin_amdgcn_perm(b.u, a.u, 0x07060302u);
}
__device__ __forceinline__ void load_lds16(const u16* g, u16* l) {
    __builtin_amdgcn_global_load_lds(
        (const __attribute__((address_space(1))) unsigned int*)g,
        (__attribute__((address_space(3))) unsigned int*)l, 16, 0, 0);
}

// ---------------------------------------------------------------------------
// Convert x + all layer weights fp32 -> bf16 (one launch, float4 granules).
// ---------------------------------------------------------------------------
__global__ __launch_bounds__(256) void cvt_all(
    const float* __restrict__ x, const float* __restrict__ W_in,
    const float* __restrict__ qkv_w, const float* __restrict__ out_w,
    const float* __restrict__ ff1_w, const float* __restrict__ ff2_w,
    u16* __restrict__ xb, u16* __restrict__ W_in_b,
    u16* __restrict__ qkv_w_b, u16* __restrict__ out_w_b,
    u16* __restrict__ ff1_w_b, u16* __restrict__ ff2_w_b)
{
    const int i = blockIdx.x * 256 + threadIdx.x;   // 0..2392063
    const float* src; u16* dst; int base;
    if (i < 1048576)      { src = x;     dst = xb;      base = 0; }
    else if (i < 1081344) { src = W_in;  dst = W_in_b;  base = 1048576; }
    else if (i < 1277952) { src = qkv_w; dst = qkv_w_b; base = 1081344; }
    else if (i < 1343488) { src = out_w; dst = out_w_b; base = 1277952; }
    else if (i < 1867776) { src = ff1_w; dst = ff1_w_b; base = 1343488; }
    else                  { src = ff2_w; dst = ff2_w_b; base = 1867776; }
    const int e = (i - base) * 4;
    const float4 v = *(const float4*)(src + e);
    ushort4 o;
    o.x = f2bf(v.x); o.y = f2bf(v.y); o.z = f2bf(v.z); o.w = f2bf(v.w);
    *(ushort4*)(dst + e) = o;
}

// ---------------------------------------------------------------------------
// bf16 MFMA GEMM, 128x128 tile, BK=32, double-buffered single-barrier K-loop.
// MODE 2: relu bf16 (ff1).
// ---------------------------------------------------------------------------
template <int MODE>
__global__ __launch_bounds__(256) void gemm_mfma(
    const u16* __restrict__ A, const u16* __restrict__ W,
    const float* __restrict__ bias, u16* __restrict__ Cb,
    int M, int N, int K)
{
    __shared__ __align__(16) u16 As[2][128 * 32];
    __shared__ __align__(16) u16 Bs[2][128 * 32];
    const int t = threadIdx.x;
    const int w = t >> 6, lane = t & 63;
    const int col = lane & 15, quad = lane >> 4;
    const int qx = (quad ^ ((col >> 1) & 3)) * 8;
    const int m0 = blockIdx.x * 128, n0 = blockIdx.y * 128;
    const int wm = (w >> 1) * 64, wn = (w & 1) * 64;

    const int r0 = lane >> 2;
    const int kc = ((lane & 3) ^ ((lane >> 3) & 3)) * 8;
    const u16* pA0 = A + (size_t)(m0 + (w * 2 + 0) * 16 + r0) * K + kc;
    const u16* pA1 = A + (size_t)(m0 + (w * 2 + 1) * 16 + r0) * K + kc;
    const u16* pB0 = W + (size_t)(n0 + (w * 2 + 0) * 16 + r0) * K + kc;
    const u16* pB1 = W + (size_t)(n0 + (w * 2 + 1) * 16 + r0) * K + kc;
    const int oA0 = (w * 2 + 0) * 512, oA1 = (w * 2 + 1) * 512;

    f32x4v acc[4][4];
#pragma unroll
    for (int i = 0; i < 4; ++i)
#pragma unroll
        for (int j = 0; j < 4; ++j) acc[i][j] = (f32x4v){0.f, 0.f, 0.f, 0.f};

    load_lds16(pA0, &As[0][oA0]);
    load_lds16(pA1, &As[0][oA1]);
    load_lds16(pB0, &Bs[0][oA0]);
    load_lds16(pB1, &Bs[0][oA1]);

    const int NIT = K >> 5;
    for (int it = 0; it < NIT; ++it) {
        const int cur = it & 1;
        __syncthreads();
        if (it + 1 < NIT) {
            const int kb = (it + 1) << 5;
            load_lds16(pA0 + kb, &As[cur ^ 1][oA0]);
            load_lds16(pA1 + kb, &As[cur ^ 1][oA1]);
            load_lds16(pB0 + kb, &Bs[cur ^ 1][oA0]);
            load_lds16(pB1 + kb, &Bs[cur ^ 1][oA1]);
        }

        frag8 a[4], b[4];
#pragma unroll
        for (int i = 0; i < 4; ++i)
            a[i] = *(const frag8*)&As[cur][(wm + i * 16 + col) * 32 + qx];
#pragma unroll
        for (int j = 0; j < 4; ++j)
            b[j] = *(const frag8*)&Bs[cur][(wn + j * 16 + col) * 32 + qx];
#pragma unroll
        for (int i = 0; i < 4; ++i)
#pragma unroll
            for (int j = 0; j < 4; ++j)
                acc[i][j] = __builtin_amdgcn_mfma_f32_16x16x32_bf16(
                    a[i], b[j], acc[i][j], 0, 0, 0);
    }

#pragma unroll
    for (int j = 0; j < 4; ++j) {
        const int cn = n0 + wn + j * 16 + col;
        const float bv = bias[cn];
#pragma unroll
        for (int i = 0; i < 4; ++i) {
            const int cmb = m0 + wm + i * 16 + quad * 4;
#pragma unroll
            for (int r = 0; r < 4; ++r) {
                float v = acc[i][j][r] + bv;
                if (MODE == 2) v = fmaxf(v, 0.f);
                Cb[(size_t)(cmb + r) * N + cn] = f2bf(v);
            }
        }
    }
}

// ---------------------------------------------------------------------------
// bf16 MFMA GEMM, 64x64 tile, BK=64, double-buffered single-barrier K-loop.
// Swizzled LDS ([64][64], chunk ^ row&7).
// MODE 1: +posenc | MODE 4: bf16 + V^T side-write (aux=vt, cols>=512)
// MODE 5: fused residual (Cb = gemm + bias + aux)
// MODE 6: A = K-split attention partials, combined during A-staging
//         (A := sum_ks Opart / sum_ks lpart), + fused residual from aux.
//         MODE 6 requires K == 256 (head dim block == K-iter).
// ---------------------------------------------------------------------------
template <int MODE>
__global__ __launch_bounds__(256) void gemm64k(
    const u16* __restrict__ A, const u16* __restrict__ W,
    const float* __restrict__ bias, u16* __restrict__ Cb,
    u16* __restrict__ aux, const float* __restrict__ lp,
    int M, int N, int K)
{
    __shared__ __align__(16) u16 As[2][64 * 64];
    __shared__ __align__(16) u16 Bs[2][64 * 64];
    const int t = threadIdx.x;
    const int w = t >> 6, lane = t & 63;
    const int col = lane & 15, quad = lane >> 4;
    const int px0 = ((quad ^ (col & 7))) * 8;
    const int px1 = px0 ^ 32;
    const int m0 = blockIdx.x * 64, n0 = blockIdx.y * 64;
    const int wm = (w >> 1) * 32, wn = (w & 1) * 32;

    const int sr = lane >> 3;
    const int lc = ((lane & 7) ^ sr) * 8;
    const u16* pA0 = A + (size_t)(m0 + w * 16 + sr) * K + lc;
    const u16* pA1 = A + (size_t)(m0 + w * 16 + 8 + sr) * K + lc;
    const u16* pB0 = W + (size_t)(n0 + w * 16 + sr) * K + lc;
    const u16* pB1 = W + (size_t)(n0 + w * 16 + 8 + sr) * K + lc;
    const int o0 = (w * 16) * 64, o1 = (w * 16 + 8) * 64;

    f32x4v acc[2][2];
#pragma unroll
    for (int i = 0; i < 2; ++i)
#pragma unroll
        for (int j = 0; j < 2; ++j) acc[i][j] = (f32x4v){0.f, 0.f, 0.f, 0.f};

    // stage A-tile for K-iter 'it' into buffer 'buf'
    auto stageA = [&](int it, int buf) {
        if (MODE == 6) {
            // combine K-split partials in VALU, write combined bf16 tile.
            const int hh = it;  // K=256: head index == K-iter
#pragma unroll
            for (int pos = 0; pos < 2; ++pos) {
                const int m = m0 + w * 16 + pos * 8 + sr;
                const int q = m & (S_LEN - 1);
                const int bh = (m >> 11) * 4 + hh;
                const size_t basei = (((size_t)bh) * S_LEN + q) * 64 + lc;
                float l = 0.f;
                float o[8] = {0.f, 0.f, 0.f, 0.f, 0.f, 0.f, 0.f, 0.f};
#pragma unroll
                for (int ksx = 0; ksx < KSPLIT; ++ksx) {
                    const uint4 pv = *(const uint4*)(A + (size_t)ksx * 16 * S_LEN * 64 + basei);
                    o[0] += bf2f((u16)(pv.x & 0xffff)); o[1] += bf2f((u16)(pv.x >> 16));
                    o[2] += bf2f((u16)(pv.y & 0xffff)); o[3] += bf2f((u16)(pv.y >> 16));
                    o[4] += bf2f((u16)(pv.z & 0xffff)); o[5] += bf2f((u16)(pv.z >> 16));
                    o[6] += bf2f((u16)(pv.w & 0xffff)); o[7] += bf2f((u16)(pv.w >> 16));
                    l += lp[((size_t)ksx * 16 + bh) * S_LEN + q];
                }
                const float inv = 1.f / l;
                uint4 pk;
                pk.x = ((u32)f2bf(o[1] * inv) << 16) | f2bf(o[0] * inv);
                pk.y = ((u32)f2bf(o[3] * inv) << 16) | f2bf(o[2] * inv);
                pk.z = ((u32)f2bf(o[5] * inv) << 16) | f2bf(o[4] * inv);
                pk.w = ((u32)f2bf(o[7] * inv) << 16) | f2bf(o[6] * inv);
                *(uint4*)&As[buf][(pos ? o1 : o0) + lane * 8] = pk;
            }
        } else {
            const int kb = it << 6;
            load_lds16(pA0 + kb, &As[buf][o0]);
            load_lds16(pA1 + kb, &As[buf][o1]);
        }
    };
    auto stageB = [&](int it, int buf) {
        const int kb = it << 6;
        load_lds16(pB0 + kb, &Bs[buf][o0]);
        load_lds16(pB1 + kb, &Bs[buf][o1]);
    };

    stageA(0, 0);
    stageB(0, 0);

    const int NIT = K >> 6;
    for (int it = 0; it < NIT; ++it) {
        const int cur = it & 1;
        __syncthreads();   // drains staging of tile 'it' + prior LDS reads
        if (it + 1 < NIT) {
            stageA(it + 1, cur ^ 1);
            stageB(it + 1, cur ^ 1);
        }
#pragma unroll
        for (int kh = 0; kh < 2; ++kh) {
            const int px = kh ? px1 : px0;
            frag8 a[2], b[2];
#pragma unroll
            for (int i = 0; i < 2; ++i)
                a[i] = *(const frag8*)&As[cur][(wm + i * 16 + col) * 64 + px];
#pragma unroll
            for (int j = 0; j < 2; ++j)
                b[j] = *(const frag8*)&Bs[cur][(wn + j * 16 + col) * 64 + px];
#pragma unroll
            for (int i = 0; i < 2; ++i)
#pragma unroll
                for (int j = 0; j < 2; ++j)
                    acc[i][j] = __builtin_amdgcn_mfma_f32_16x16x32_bf16(
                        a[i], b[j], acc[i][j], 0, 0, 0);
        }
    }

#pragma unroll
    for (int j = 0; j < 2; ++j) {
        const int cn = n0 + wn + j * 16 + col;
        const float bv = bias[cn];
#pragma unroll
        for (int i = 0; i < 2; ++i) {
            const int cmb = m0 + wm + i * 16 + quad * 4;
            float vv[4];
#pragma unroll
            for (int r = 0; r < 4; ++r) {
                float v = acc[i][j][r] + bv;
                if (MODE == 1) v += pe_val((cmb + r) & (S_LEN - 1), cn);
                if (MODE == 5 || MODE == 6)
                    v += bf2f(aux[(size_t)(cmb + r) * N + cn]);
                vv[r] = v;
                Cb[(size_t)(cmb + r) * N + cn] = f2bf(v);
            }
            if (MODE == 4 && cn >= 512) {   // V^T side-write: vt[bh][d][s]
                const int dg = cn - 512;
                const int bh = (cmb >> 11) * 4 + (dg >> 6);
                uint2 pk;
                pk.x = ((u32)f2bf(vv[1]) << 16) | f2bf(vv[0]);
                pk.y = ((u32)f2bf(vv[3]) << 16) | f2bf(vv[2]);
                *(uint2*)&aux[((size_t)bh * 64 + (dg & 63)) * S_LEN + (cmb & 2047)] = pk;
            }
        }
    }
}

// ---------------------------------------------------------------------------
// Flash attention, K-split partial pass. Double-buffered single-barrier loop
// at 40 KB LDS (4 blocks/CU). QK^T phase shares each K-frag read across BOTH
// q-groups (K held in regs); qg1's packed P is held in 8 VGPRs and written to
// the compact 8 KB Ps buffer after qg0's pf read retires (in-order per-wave
// DS makes the WAR safe). No-max softmax; scale folded into bf16 Q frags;
// lsum via ones-MFMA; partial O bf16.
// ---------------------------------------------------------------------------
__global__ __launch_bounds__(256) void attn_part(const u16* __restrict__ qkv,
                                                 const u16* __restrict__ vt,
                                                 u16* __restrict__ Opart,
                                                 float* __restrict__ lpart)
{
    __shared__ __align__(16) u16 Ks[2][2][64 * 32];   // [buf][k-half]
    __shared__ __align__(16) u16 Vt[2][2][64 * 32];
    __shared__ __align__(16) u16 Ps[4][2][512];       // [wave][key-half] (qg-shared)

    const int t = threadIdx.x;
    const int w = t >> 6, lane = t & 63;
    const int col = lane & 15, quad = lane >> 4;
    const int sq = (col >> 1) & 3;
    const int qx = (quad ^ sq) * 8;
    const int bh = blockIdx.x, b = bh >> 2, hh = bh & 3;
    const int qt = blockIdx.y, ks = blockIdx.z;

    const float SCL = 0.125f * 1.44269504f;  // log2(e)/8, folded into Q

    frag8 qf[2][2];
#pragma unroll
    for (int qg = 0; qg < 2; ++qg) {
        const int qrow = qt * 128 + w * 32 + qg * 16 + col;
        const u16* qp = qkv + (size_t)(b * S_LEN + qrow) * 768 + hh * HDIM;
        const frag8 r0 = *(const frag8*)(qp + quad * 8);
        const frag8 r1 = *(const frag8*)(qp + 32 + quad * 8);
#pragma unroll
        for (int e = 0; e < 8; ++e) {
            qf[qg][0][e] = (short)f2bf(bf2f((u16)r0[e]) * SCL);
            qf[qg][1][e] = (short)f2bf(bf2f((u16)r1[e]) * SCL);
        }
    }
    frag8 ones;
#pragma unroll
    for (int e = 0; e < 8; ++e) ones[e] = (short)0x3F80;  // bf16 1.0

    f32x4v Oacc[2][4], lacc[2];
#pragma unroll
    for (int qg = 0; qg < 2; ++qg) {
#pragma unroll
        for (int dt = 0; dt < 4; ++dt) Oacc[qg][dt] = (f32x4v){0.f, 0.f, 0.f, 0.f};
        lacc[qg] = (f32x4v){0.f, 0.f, 0.f, 0.f};
    }

    const int srow = w * 16 + (lane >> 2);
    const int sseg = ((lane & 3) ^ ((lane >> 3) & 3)) * 8;
    const int kb0 = ks * (S_LEN / KSPLIT);
    const u16* kbase = qkv + (size_t)(b * S_LEN + kb0 + srow) * 768
                       + 256 + hh * HDIM + sseg;
    const u16* vbase = vt + ((size_t)bh * 64 + srow) * S_LEN + kb0 + sseg;
    const int so = w * 512;

    load_lds16(kbase, &Ks[0][0][so]);
    load_lds16(kbase + 32, &Ks[0][1][so]);
    load_lds16(vbase, &Vt[0][0][so]);
    load_lds16(vbase + 32, &Vt[0][1][so]);

    const int NT = S_LEN / KSPLIT / 64;   // 8 tiles
    for (int kt = 0; kt < NT; ++kt) {
        const int cur = kt & 1;
        __syncthreads();   // drains staging of tile kt + prior LDS reads
        if (kt + 1 < NT) {
            const u16* kp = kbase + (size_t)(kt + 1) * 64 * 768;
            const u16* vp = vbase + (kt + 1) * 64;
            load_lds16(kp, &Ks[cur ^ 1][0][so]);
            load_lds16(kp + 32, &Ks[cur ^ 1][1][so]);
            load_lds16(vp, &Vt[cur ^ 1][0][so]);
            load_lds16(vp + 32, &Vt[cur ^ 1][1][so]);
        }

        // ---- S^T = K Q^T: K frags read ONCE, both q-groups computed; qg0's
        // P goes to Ps immediately, qg1's packed P held in regs. ----
        frag8 pf[2][2];
        uint2 held[4];
#pragma unroll
        for (int nt = 0; nt < 4; ++nt) {
            const frag8 k0 = *(const frag8*)&Ks[cur][0][(nt * 16 + col) * 32 + qx];
            const frag8 k1 = *(const frag8*)&Ks[cur][1][(nt * 16 + col) * 32 + qx];
            const int c = (nt & 1) * 2 + (quad >> 1);
            const int poff = col * 32 + ((c ^ sq) * 8) + (quad & 1) * 4;

            f32x4v s0 = (f32x4v){0.f, 0.f, 0.f, 0.f};
            s0 = __builtin_amdgcn_mfma_f32_16x16x32_bf16(k0, qf[0][0], s0, 0, 0, 0);
            s0 = __builtin_amdgcn_mfma_f32_16x16x32_bf16(k1, qf[0][1], s0, 0, 0, 0);
            f32x4v s1 = (f32x4v){0.f, 0.f, 0.f, 0.f};
            s1 = __builtin_amdgcn_mfma_f32_16x16x32_bf16(k0, qf[1][0], s1, 0, 0, 0);
            s1 = __builtin_amdgcn_mfma_f32_16x16x32_bf16(k1, qf[1][1], s1, 0, 0, 0);

            uint2 pk;
            pk.x = pk2bf(__builtin_amdgcn_exp2f(s0[0]), __builtin_amdgcn_exp2f(s0[1]));
            pk.y = pk2bf(__builtin_amdgcn_exp2f(s0[2]), __builtin_amdgcn_exp2f(s0[3]));
            *(uint2*)&Ps[w][nt >> 1][poff] = pk;

            held[nt].x = pk2bf(__builtin_amdgcn_exp2f(s1[0]), __builtin_amdgcn_exp2f(s1[1]));
            held[nt].y = pk2bf(__builtin_amdgcn_exp2f(s1[2]), __builtin_amdgcn_exp2f(s1[3]));
        }
        pf[0][0] = *(const frag8*)&Ps[w][0][col * 32 + qx];
        pf[0][1] = *(const frag8*)&Ps[w][1][col * 32 + qx];
#pragma unroll
        for (int nt = 0; nt < 4; ++nt) {
            const int c = (nt & 1) * 2 + (quad >> 1);
            const int poff = col * 32 + ((c ^ sq) * 8) + (quad & 1) * 4;
            *(uint2*)&Ps[w][nt >> 1][poff] = held[nt];
        }
        pf[1][0] = *(const frag8*)&Ps[w][0][col * 32 + qx];
        pf[1][1] = *(const frag8*)&Ps[w][1][col * 32 + qx];

        // ---- O^T += V^T P^T; both q-groups share each V frag read ----
#pragma unroll
        for (int dt = 0; dt < 4; ++dt) {
            const frag8 v0 = *(const frag8*)&Vt[cur][0][(dt * 16 + col) * 32 + qx];
            const frag8 v1 = *(const frag8*)&Vt[cur][1][(dt * 16 + col) * 32 + qx];
#pragma unroll
            for (int qg = 0; qg < 2; ++qg) {
                Oacc[qg][dt] = __builtin_amdgcn_mfma_f32_16x16x32_bf16(
                    v0, pf[qg][0], Oacc[qg][dt], 0, 0, 0);
                Oacc[qg][dt] = __builtin_amdgcn_mfma_f32_16x16x32_bf16(
                    v1, pf[qg][1], Oacc[qg][dt], 0, 0, 0);
            }
        }
#pragma unroll
        for (int qg = 0; qg < 2; ++qg) {
            lacc[qg] = __builtin_amdgcn_mfma_f32_16x16x32_bf16(
                ones, pf[qg][0], lacc[qg], 0, 0, 0);
            lacc[qg] = __builtin_amdgcn_mfma_f32_16x16x32_bf16(
                ones, pf[qg][1], lacc[qg], 0, 0, 0);
        }
    }

#pragma unroll
    for (int qg = 0; qg < 2; ++qg) {
        const int qrow = qt * 128 + w * 32 + qg * 16 + col;
        u16* op = Opart + (((size_t)ks * 16 + bh) * S_LEN + qrow) * 64;
#pragma unroll
        for (int dt = 0; dt < 4; ++dt) {
            uint2 pk;
            pk.x = pk2bf(Oacc[qg][dt][0], Oacc[qg][dt][1]);
            pk.y = pk2bf(Oacc[qg][dt][2], Oacc[qg][dt][3]);
            *(uint2*)(op + dt * 16 + quad * 4) = pk;
        }
        if (quad == 0)
            lpart[((size_t)ks * 16 + bh) * S_LEN + qrow] = lacc[qg][0];
    }
}

// ---------------------------------------------------------------------------
// hb = LayerNorm(sab) * w + b, one WAVE per row (no LDS, no barriers).
// ---------------------------------------------------------------------------
__global__ __launch_bounds__(256) void ln_wave(u16* __restrict__ hb,
                                               const u16* __restrict__ sab,
                                               const float* __restrict__ w,
                                               const float* __restrict__ b)
{
    const int t = threadIdx.x;
    const int wv = t >> 6, lane = t & 63;
    const int row = blockIdx.x * 4 + wv;
    const size_t base = (size_t)row * DMODEL + lane * 4;

    const ushort4 xv = *(const ushort4*)&sab[base];
    const float x0 = bf2f(xv.x), x1 = bf2f(xv.y);
    const float x2 = bf2f(xv.z), x3 = bf2f(xv.w);

    float s = (x0 + x1) + (x2 + x3);
    float s2 = (x0 * x0 + x1 * x1) + (x2 * x2 + x3 * x3);
#pragma unroll
    for (int msk = 1; msk < 64; msk <<= 1) {
        s += __shfl_xor(s, msk);
        s2 += __shfl_xor(s2, msk);
    }
    const float mu = s * (1.f / DMODEL);
    const float var = s2 * (1.f / DMODEL) - mu * mu;
    const float rs = rsqrtf(var + EPSV);

    const float4 wv4 = *(const float4*)&w[lane * 4];
    const float4 bv4 = *(const float4*)&b[lane * 4];
    ushort4 o;
    o.x = f2bf((x0 - mu) * rs * wv4.x + bv4.x);
    o.y = f2bf((x1 - mu) * rs * wv4.y + bv4.y);
    o.z = f2bf((x2 - mu) * rs * wv4.z + bv4.z);
    o.w = f2bf((x3 - mu) * rs * wv4.w + bv4.w);
    *(ushort4*)&hb[base] = o;
}

__global__ __launch_bounds__(256) void final_proj(const u16* __restrict__ hb,
                                                  const float* __restrict__ Wfc,
                                                  const float* __restrict__ bfc,
                                                  float* __restrict__ out)
{
    const int idx = blockIdx.x * 256 + threadIdx.x;
    const int b = idx >> 9;
    const int o = idx & 511;
    const u16* hp = hb + (size_t)(b * S_LEN + S_LEN - 1) * DMODEL;
    const float* wp = Wfc + (size_t)o * DMODEL;
    float s = 0.f;
#pragma unroll 4
    for (int d = 0; d < DMODEL; ++d) s += bf2f(hp[d]) * wp[d];
    out[idx] = s + bfc[o];
}

extern "C" void kernel_launch(void* const* d_in, const int* in_sizes, int n_in,
                              void* d_out, int out_size, void* d_ws, size_t ws_size,
                              hipStream_t stream)
{
    const float* x     = (const float*)d_in[0];
    const float* W_in  = (const float*)d_in[1];
    const float* b_in  = (const float*)d_in[2];
    const float* qkv_w = (const float*)d_in[3];
    const float* qkv_b = (const float*)d_in[4];
    const float* out_w = (const float*)d_in[5];
    const float* out_b = (const float*)d_in[6];
    const float* ln1_w = (const float*)d_in[7];
    const float* ln1_b = (const float*)d_in[8];
    const float* ff1_w = (const float*)d_in[9];
    const float* ff1_b = (const float*)d_in[10];
    const float* ff2_w = (const float*)d_in[11];
    const float* ff2_b = (const float*)d_in[12];
    const float* ln2_w = (const float*)d_in[13];
    const float* ln2_b = (const float*)d_in[14];
    const float* W_fc  = (const float*)d_in[15];
    const float* b_fc  = (const float*)d_in[16];
    float* out = (float*)d_out;

    char* p = (char*)d_ws;
    u16* hb    = (u16*)p;  p += (size_t)NTOK * DMODEL * 2;   // 4 MB
    u16* sab   = (u16*)p;  p += (size_t)NTOK * DMODEL * 2;   // 4 MB
    u16* xb    = (u16*)p;  p += (size_t)NTOK * INDIM * 2;    // 8 MB
    u16* qkvb  = (u16*)p;  p += (size_t)NTOK * 768 * 2;      // 12 MB
    u16* ffb   = (u16*)p;  p += (size_t)NTOK * FFDIM * 2;    // 32 MB
    u16* vtb   = (u16*)p;  p += (size_t)16 * 64 * S_LEN * 2; // 4 MB
    float* lpart = (float*)p; p += (size_t)KSPLIT * 16 * S_LEN * 4; // 512 KB
    u16* W_in_b  = (u16*)p; p += (size_t)131072 * 2;
    u16* qkv_w_b = (u16*)p; p += (size_t)786432 * 2;
    u16* out_w_b = (u16*)p; p += (size_t)262144 * 2;
    u16* ff1_w_b = (u16*)p; p += (size_t)2097152 * 2;
    u16* ff2_w_b = (u16*)p; p += (size_t)2097152 * 2;
    if (ws_size < (size_t)78643200) return;

    u16* Opart = ffb;   // aliases ffb (disjoint lifetime within layer)

    cvt_all<<<9344, 256, 0, stream>>>(x, W_in, qkv_w, out_w, ff1_w, ff2_w,
                                      xb, W_in_b, qkv_w_b, out_w_b, ff1_w_b, ff2_w_b);

    // input projection + posenc -> hb (bf16)
    gemm64k<1><<<dim3(NTOK / 64, DMODEL / 64), 256, 0, stream>>>(
        xb, W_in_b, b_in, hb, nullptr, nullptr, NTOK, DMODEL, INDIM);

    for (int l = 0; l < NLAYER; ++l) {
        gemm64k<4><<<dim3(NTOK / 64, 768 / 64), 256, 0, stream>>>(
            hb, qkv_w_b + (size_t)l * 768 * DMODEL, qkv_b + l * 768,
            qkvb, vtb, nullptr, NTOK, 768, DMODEL);
        attn_part<<<dim3(BATCH * NHEAD, S_LEN / 128, KSPLIT), 256, 0, stream>>>(
            qkvb, vtb, Opart, lpart);
        // out-proj with fused K-split combine (A = Opart) + residual (aux = hb)
        gemm64k<6><<<dim3(NTOK / 64, DMODEL / 64), 256, 0, stream>>>(
            Opart, out_w_b + (size_t)l * DMODEL * DMODEL, out_b + l * DMODEL,
            sab, hb, lpart, NTOK, DMODEL, DMODEL);
        ln_wave<<<NTOK / 4, 256, 0, stream>>>(hb, sab, ln1_w + l * DMODEL, ln1_b + l * DMODEL);
        gemm_mfma<2><<<dim3(NTOK / 128, FFDIM / 128), 256, 0, stream>>>(
            hb, ff1_w_b + (size_t)l * FFDIM * DMODEL, ff1_b + l * FFDIM,
            ffb, NTOK, FFDIM, DMODEL);
        gemm64k<5><<<dim3(NTOK / 64, DMODEL / 64), 256, 0, stream>>>(
            ffb, ff2_w_b + (size_t)l * DMODEL * FFDIM, ff2_b + l * DMODEL,
            sab, hb, nullptr, NTOK, DMODEL, FFDIM);
        ln_wave<<<NTOK / 4, 256, 0, stream>>>(hb, sab, ln2_w + l * DMODEL, ln2_b + l * DMODEL);
    }

    final_proj<<<8, 256, 0, stream>>>(hb, W_fc, b_fc, out);
}